// Round 1
// baseline (370.562 us; speedup 1.0000x reference)
//
#include <hip/hip_runtime.h>
#include <hip/hip_bf16.h>

// ZeroPadder: out[b,t,0:1024] = x[b,t,:], out[b,t,1024:2048] = 0
// x: [16, 2048, 1024] f32 -> out: [16, 2048, 2048] f32
// Pure memory-bound copy+zero; float4 vectorized, grid-stride.

#define OUT_ROW4 512   // 2048 floats / 4 per float4
#define IN_ROW4  256   // 1024 floats / 4 per float4

__global__ __launch_bounds__(256) void ZeroPadder_19490561590035_kernel(
    const float4* __restrict__ x, float4* __restrict__ out, int total4) {
    int idx = blockIdx.x * blockDim.x + threadIdx.x;
    int stride = gridDim.x * blockDim.x;
    for (int v = idx; v < total4; v += stride) {
        int row = v >> 9;        // v / OUT_ROW4
        int c   = v & 511;       // v % OUT_ROW4
        float4 val;
        if (c < IN_ROW4) {
            val = x[(row << 8) + c];   // row * IN_ROW4 + c
        } else {
            val = make_float4(0.f, 0.f, 0.f, 0.f);
        }
        out[v] = val;
    }
}

extern "C" void kernel_launch(void* const* d_in, const int* in_sizes, int n_in,
                              void* d_out, int out_size, void* d_ws, size_t ws_size,
                              hipStream_t stream) {
    const float4* x = (const float4*)d_in[0];
    // d_in[1] (the identity+zero weight) is unused: the matmul is a zero-pad.
    float4* out = (float4*)d_out;
    int total4 = out_size / 4;   // 16*2048*2048 / 4 = 16,777,216

    int block = 256;
    int grid  = 2048;            // 256 CUs x 8 blocks/CU; grid-stride covers the rest
    ZeroPadder_19490561590035_kernel<<<grid, block, 0, stream>>>(x, out, total4);
}

// Round 6
// 361.091 us; speedup vs baseline: 1.0262x; 1.0262x over previous
//
#include <hip/hip_runtime.h>
#include <hip/hip_bf16.h>

// ZeroPadder: out[b,t,0:1024] = x[b,t,:], out[b,t,1024:2048] = 0
// x: [16, 2048, 1024] f32 -> out: [16, 2048, 2048] f32.
// Pure streaming copy+zero. 384 MiB total traffic -> ~60 us floor @ 6.3 TB/s.
//
// Structure: 524,288 threads; each does exactly 16 copy-chunks (float4) and
// 16 zero-chunks, no bounds checks, no branches. Non-temporal loads/stores:
// data is touched exactly once, so bypass L2 allocation (384 MiB >> 32 MiB L2).
//
// Index math: copy chunk c (x-linear float4 index, c = row*256 + col) lands at
// out chunk row*512 + col = c + (c & ~255). Zero chunk z lands at
// z + (z & ~255) + 256.

typedef float f32x4 __attribute__((ext_vector_type(4)));

#define THREADS 256
#define BLOCKS  2048
#define T_TOTAL (THREADS * BLOCKS)   // 524288
#define ITERS   16                   // 16 * 524288 = 8,388,608 chunks per half

__global__ __launch_bounds__(THREADS) void ZeroPadder_19490561590035_kernel(
    const f32x4* __restrict__ x, f32x4* __restrict__ out) {
    const int t = blockIdx.x * THREADS + threadIdx.x;

    const f32x4 z = {0.f, 0.f, 0.f, 0.f};

    // Zero half: pure write stream (fire-and-forget, saturates write channels
    // while the copy loads below are in flight after scheduling).
    #pragma unroll
    for (int i = 0; i < ITERS; ++i) {
        int c = t + i * T_TOTAL;
        int d = c + (c & ~255) + 256;
        __builtin_nontemporal_store(z, &out[d]);
    }

    // Copy half: 16 independent load->store pairs; unrolled so the compiler
    // batches loads (vmcnt) ahead of the dependent stores.
    #pragma unroll
    for (int i = 0; i < ITERS; ++i) {
        int c = t + i * T_TOTAL;
        f32x4 v = __builtin_nontemporal_load(&x[c]);
        int d = c + (c & ~255);
        __builtin_nontemporal_store(v, &out[d]);
    }
}

extern "C" void kernel_launch(void* const* d_in, const int* in_sizes, int n_in,
                              void* d_out, int out_size, void* d_ws, size_t ws_size,
                              hipStream_t stream) {
    const f32x4* x = (const f32x4*)d_in[0];
    // d_in[1] (identity+zero weight) unused: the matmul is a pure zero-pad.
    f32x4* out = (f32x4*)d_out;
    ZeroPadder_19490561590035_kernel<<<BLOCKS, THREADS, 0, stream>>>(x, out);
}